// Round 13
// baseline (186.996 us; speedup 1.0000x reference)
//
#include <hip/hip_runtime.h>
#include <stdint.h>

#define BATCH 8
#define NPRI 100000
#define NGT 16
#define NCLS 41
#define F_POS_TH 0.5f
#define F_NEG_TH 0.4f

static constexpr int TPB = 256;
static constexpr int MCHUNK = 16;  // prior-chunks per (b,g) in k_match
static constexpr int MLEN = (NPRI + MCHUNK - 1) / MCHUNK; // 6250

// k_conf geometry: 4-wave blocks, each wave owns a 64-row tile, pure-register
static constexpr int TILES_PER_B = (NPRI + 63) / 64;  // 1563
static constexpr int CBLK = (TILES_PER_B + 3) / 4;    // 391 blocks per batch
static constexpr int CW = 64 * NCLS / 4;              // 656 f32x4 chunks per tile
static constexpr int H0BIN = 256;                     // lvl0 hist bins (key top-8 bits)
static constexpr int NBIN = 4096;                     // k_select lvl1/2 bins

// ---- workspace layout (bytes) ----
static constexpr size_t OFF_KEY  = 0;                               // u32 [B*P] lc bits
static constexpr size_t OFF_GTC  = OFF_KEY + (size_t)BATCH*NPRI*4;  // u64 [B*16]
static constexpr size_t OFF_HG   = OFF_GTC + BATCH*NGT*8;           // u32 [B][256] lvl0 hist
static constexpr size_t OFF_NPOS = OFF_HG + (size_t)BATCH*H0BIN*4;  // u32 [B]
static constexpr size_t OFF_SL1  = OFF_NPOS + BATCH*4;              // f32 [B]
static constexpr size_t OFF_CEP  = OFF_SL1  + BATCH*4;              // f32 [B]
static constexpr size_t OFF_NEG  = OFF_CEP  + BATCH*4;              // f32 [B]
static constexpr size_t OFF_FTK  = OFF_NEG  + BATCH*4;              // u32 [1]
static constexpr int ZERO_U32 = (int)((OFF_FTK + 4 - OFF_HG) / 4);  // hist + scalars

typedef float f32x4 __attribute__((ext_vector_type(4)));

__device__ inline float smoothl1(float d) {
  float a = fabsf(d);
  return a < 1.f ? 0.5f * d * d : a - 0.5f;
}
__device__ inline float aload_f32(const float* p) {
  return __hip_atomic_load(p, __ATOMIC_RELAXED, __HIP_MEMORY_SCOPE_AGENT);
}

// ---------------- K_init: zero hist+scalars, gtc baseline ----------------
// gtc re-based every call: ws poison 0xAA.. would win atomicMax otherwise.
__global__ void k_init(unsigned* __restrict__ z, unsigned long long* __restrict__ gtc) {
  int t = threadIdx.x;  // 512 threads
  for (int i = t; i < ZERO_U32; i += 512) z[i] = 0u;
  if (t < BATCH * NGT) gtc[t] = 0xFFFFFFFFull;  // (iou=0)<<32 | (0xFFFFFFFF - p=0)
}

// ---------------- K_match: grid (chunk, b*g); tree-reduce, 1 atomic/block ----------------
__global__ __launch_bounds__(TPB) void k_match(const float* __restrict__ priors,
                                               const float* __restrict__ gtb,
                                               unsigned long long* __restrict__ gtc) {
  int bg = blockIdx.y;
  int t = threadIdx.x;
  const f32x4 gv = ((const f32x4*)gtb)[bg];
  float garea = (gv[2] - gv[0]) * (gv[3] - gv[1]);
  int pend = min(NPRI, (int)(blockIdx.x + 1) * MLEN);
  unsigned long long best = 0;
  for (int p = blockIdx.x * MLEN + t; p < pend; p += TPB) {
    f32x4 pv = ((const f32x4*)priors)[p];
    float px1 = pv[0] - 0.5f * pv[2], py1 = pv[1] - 0.5f * pv[3];
    float px2 = pv[0] + 0.5f * pv[2], py2 = pv[1] + 0.5f * pv[3];
    float ix = fmaxf(fminf(px2, gv[2]) - fmaxf(px1, gv[0]), 0.f);
    float iy = fmaxf(fminf(py2, gv[3]) - fmaxf(py1, gv[1]), 0.f);
    float inter = ix * iy;
    float parea = (px2 - px1) * (py2 - py1);
    float iou = inter / (parea + garea - inter);
    unsigned long long comp = ((unsigned long long)__float_as_uint(iou) << 32)
                            | (unsigned long long)(0xFFFFFFFFu - (unsigned)p);
    best = best > comp ? best : comp;
  }
#pragma unroll
  for (int off = 32; off; off >>= 1) {
    unsigned long long o = (unsigned long long)__shfl_xor((long long)best, off, 64);
    best = best > o ? best : o;
  }
  __shared__ unsigned long long red[4];
  if ((t & 63) == 0) red[t >> 6] = best;
  __syncthreads();
  if (t == 0) {
    unsigned long long r = red[0];
    r = r > red[1] ? r : red[1];
    r = r > red[2] ? r : red[2];
    r = r > red[3] ? r : red[3];
    atomicMax(&gtc[bg], r);
  }
}

// ---------------- K_conf: register-coalesced, per-wave LDS-atomic row reduce ----------------
// Each wave owns a 64-row tile. 11 coalesced f32x4 loads/lane hold the tile in
// registers; exp-sums scatter into a per-wave sums[64] slice via LDS float
// atomics (single-wave -> deterministic order, ds ops in program order).
__global__ __launch_bounds__(256, 4) void k_conf(
    const float* __restrict__ loc, const float* __restrict__ conf,
    const float* __restrict__ priors, const float* __restrict__ gtb,
    const int* __restrict__ gtl, const unsigned long long* __restrict__ gtc,
    unsigned* __restrict__ key, unsigned* __restrict__ histg,
    unsigned* __restrict__ npos, float* __restrict__ sl1sum, float* __restrict__ cepos) {
  __shared__ float sums[4][64];
  __shared__ float r0s[4][64];
  __shared__ unsigned hcb[H0BIN];
  __shared__ float redS[4], redC[4]; __shared__ unsigned redP[4];
  const int t = threadIdx.x, w = t >> 6, l = t & 63;
  const int b = blockIdx.y;
  const int tile = blockIdx.x * 4 + w;
  hcb[t] = 0u;           // t < 256 == H0BIN
  sums[w][l] = 0.f;      // own-wave slice; no barrier needed before own-wave use
  __syncthreads();       // hcb zeroing visible to all waves
  float accS = 0.f, accC = 0.f; unsigned accP = 0;
  if (tile < TILES_PER_B) {
    const f32x4* c4 = (const f32x4*)conf;
    const size_t base = (size_t)b * (NPRI * NCLS / 4) + (size_t)tile * CW;
    const size_t bend = (size_t)(b + 1) * (NPRI * NCLS / 4) - 1;
    // ---- 11 coalesced, aligned, unconditional (clamped) loads ----
    f32x4 rr[11];
#pragma unroll
    for (int u = 0; u < 11; u++) {
      size_t ix = base + (unsigned)(u * 64 + l);
      if (ix > bend) ix = bend;  // dupes land in rows >= batch end: discarded below
      rr[u] = c4[ix];
    }
    const int p = tile * 64 + l;
    const bool valid = p < NPRI;
    const int pc = valid ? p : NPRI - 1;
    const f32x4 pv = ((const f32x4*)priors)[pc];
    const f32x4 ld = ((const f32x4*)loc)[(size_t)b * NPRI + pc];
    // ---- scatter exp-sums per row + class-0 capture ----
#pragma unroll
    for (int u = 0; u < 11; u++) {
      int cidx = u * 64 + l;
      if (cidx < CW) {             // compute predicated; loads were unconditional
        int f = cidx * 4;          // float offset within tile
        int r0 = (int)((unsigned)f / 41u);
        int rem = f - r0 * 41;     // class of element 0
        float e0 = __expf(rr[u][0]);
        float e1 = __expf(rr[u][1]);
        float e2 = __expf(rr[u][2]);
        float e3 = __expf(rr[u][3]);
        int nlo = 41 - rem;        // elements belonging to row r0
        float slo = e0, shi = 0.f;
        if (nlo > 1) slo += e1; else shi += e1;
        if (nlo > 2) slo += e2; else shi += e2;
        if (nlo > 3) slo += e3; else shi += e3;
        atomicAdd(&sums[w][r0], slo);
        if (nlo <= 3) atomicAdd(&sums[w][r0 + 1], shi);  // never fires at r0==63
        if (rem == 0) r0s[w][r0] = rr[u][0];             // class0 of row r0
        else if (nlo <= 3) {                             // class0 of row r0+1
          float v = (nlo == 1) ? rr[u][1] : (nlo == 2) ? rr[u][2] : rr[u][3];
          r0s[w][r0 + 1] = v;
        }
      }
    }
    // same-wave ds ops complete in program order: safe to read own slice
    float lse = __logf(sums[w][l]);
    float r0v = r0s[w][l];
    if (valid) {
      // per-prior match (bit-identical iou math to k_match)
      float px1 = pv[0] - 0.5f * pv[2], py1 = pv[1] - 0.5f * pv[3];
      float px2 = pv[0] + 0.5f * pv[2], py2 = pv[1] + 0.5f * pv[3];
      float parea = (px2 - px1) * (py2 - py1);
      float bov = 0.f; int g = 0;
#pragma unroll
      for (int gg = 0; gg < NGT; gg++) {
        const f32x4 gv = ((const f32x4*)gtb)[b * NGT + gg];
        float ix = fmaxf(fminf(px2, gv[2]) - fmaxf(px1, gv[0]), 0.f);
        float iy = fmaxf(fminf(py2, gv[3]) - fmaxf(py1, gv[1]), 0.f);
        float inter = ix * iy;
        float garea = (gv[2] - gv[0]) * (gv[3] - gv[1]);
        float iou = inter / (parea + garea - inter);
        if (iou > bov) { bov = iou; g = gg; }
      }
      float o = bov;
#pragma unroll
      for (int gg = 0; gg < NGT; gg++) {   // force-match, last-wins
        unsigned long long c64 = gtc[b * NGT + gg];
        unsigned pw = 0xFFFFFFFFu - (unsigned)(c64 & 0xFFFFFFFFull);
        if ((unsigned)p == pw) { o = 2.0f; g = gg; }
      }
      int c = gtl[b * NGT + g];
      if (o < F_POS_TH) c = -1;
      if (o < F_NEG_TH) c = 0;
      unsigned kkreg = (c == 0) ? __float_as_uint(lse - r0v) : 0u;
      key[(size_t)b * NPRI + p] = kkreg;
      atomicAdd(&hcb[kkreg >> 24], 1u);
      if (c > 0) {
        accP = 1;
        float rc = conf[((size_t)b * NPRI + p) * NCLS + c];  // rare scattered re-read
        accC = lse - rc;
        const f32x4 gvb = ((const f32x4*)gtb)[b * NGT + g];
        float tx = ((gvb[0] + gvb[2]) * 0.5f - pv[0]) / (0.1f * pv[2]);
        float ty = ((gvb[1] + gvb[3]) * 0.5f - pv[1]) / (0.1f * pv[3]);
        float tw = __logf(fmaxf((gvb[2] - gvb[0]) / pv[2], 1e-8f)) / 0.2f;
        float th = __logf(fmaxf((gvb[3] - gvb[1]) / pv[3], 1e-8f)) / 0.2f;
        accS = smoothl1(ld[0] - tx) + smoothl1(ld[1] - ty)
             + smoothl1(ld[2] - tw) + smoothl1(ld[3] - th);
      }
    }
  }
  __syncthreads();  // hcb atomics visible block-wide
  { unsigned v = hcb[t]; if (v) atomicAdd(&histg[b * H0BIN + t], v); }
  // block reduction, one atomic set per block
  float vs = accS, vc = accC; unsigned vp = accP;
#pragma unroll
  for (int off = 32; off; off >>= 1) {
    vs += __shfl_down(vs, off, 64);
    vc += __shfl_down(vc, off, 64);
    vp += __shfl_down(vp, off, 64);
  }
  if (l == 0) { redS[w] = vs; redC[w] = vc; redP[w] = vp; }
  __syncthreads();
  if (t == 0) {
    float ts = redS[0] + redS[1] + redS[2] + redS[3];
    float tc = redC[0] + redC[1] + redC[2] + redC[3];
    unsigned tp = redP[0] + redP[1] + redP[2] + redP[3];
    if (tp) atomicAdd(&npos[b], tp);
    if (ts != 0.f) atomicAdd(&sl1sum[b], ts);
    if (tc != 0.f) atomicAdd(&cepos[b], tc);
  }
}

// ---------------- K_select: lvl0 prebuilt (8b) + lvl1 [23:12] + lvl2 [11:0]; exact-T sum ----------------
__global__ __launch_bounds__(1024) void k_select(
    const unsigned* __restrict__ key, const unsigned* __restrict__ histg,
    const unsigned* __restrict__ npos, const float* __restrict__ sl1sum,
    const float* __restrict__ cepos, float* __restrict__ negsum,
    unsigned* __restrict__ final_tk, float* __restrict__ out) {
  __shared__ unsigned hc[NBIN];
  __shared__ unsigned pcs[256], sc[256];
  __shared__ int wA; __shared__ unsigned kexA;
  __shared__ unsigned kS, prefS;
  __shared__ float redf[16];
  int b = blockIdx.x, t = threadIdx.x;
  unsigned k0 = min(3u * npos[b], (unsigned)(NPRI - 1));
  const int iters = (NPRI + 1023) / 1024;
  // ---- lvl0: 256-bin prebuilt hist, suffix scan ----
  if (t < 256) { unsigned v = histg[b * H0BIN + t]; pcs[t] = v; sc[t] = v; }
  if (t == 0) { kS = 0u; prefS = 0u; wA = -1; }
  __syncthreads();
  for (int off = 1; off < 256; off <<= 1) {
    unsigned v = 0;
    if (t < 256) v = (t + off < 256) ? sc[t + off] : 0u;
    __syncthreads();
    if (t < 256) sc[t] += v;
    __syncthreads();
  }
  if (t < 256) {
    unsigned excl = sc[t] - pcs[t];
    if (k0 > 0 && excl < k0 && k0 <= excl + pcs[t]) { wA = t; kexA = excl; }
  }
  __syncthreads();
  if (t == 0 && wA >= 0) { prefS = ((unsigned)wA) << 24; kS = k0 - kexA; }
  __syncthreads();
  // ---- lvl1/lvl2: 12-bit scans over near-uniform mantissa bits ----
  for (int lvl = 1; lvl <= 2; lvl++) {
    unsigned k = kS;
    int shift = (lvl == 1) ? 12 : 0;
    int lowcut = (lvl == 1) ? 24 : 12;
    for (int i = t; i < NBIN; i += 1024) hc[i] = 0u;
    if (t == 0) wA = -1;
    __syncthreads();
    unsigned pre = prefS >> lowcut;
    if (k > 0) {
      for (int n = 0; n < iters; n++) {
        int i = n * 1024 + t;
        if (i < NPRI) {
          unsigned kk = key[(size_t)b * NPRI + i];
          if ((kk >> lowcut) == pre) atomicAdd(&hc[(kk >> shift) & 0xFFFu], 1u);
        }
      }
    }
    __syncthreads();
    if (t < 256) {
      unsigned cs = 0;
#pragma unroll
      for (int u = 0; u < 16; u++) cs += hc[t * 16 + u];
      pcs[t] = cs; sc[t] = cs;
    }
    __syncthreads();
    for (int off = 1; off < 256; off <<= 1) {
      unsigned v = 0;
      if (t < 256) v = (t + off < 256) ? sc[t + off] : 0u;
      __syncthreads();
      if (t < 256) sc[t] += v;
      __syncthreads();
    }
    if (t < 256) {
      unsigned excl = sc[t] - pcs[t];
      if (k > 0 && excl < k && k <= excl + pcs[t]) { wA = t; kexA = excl; }
    }
    __syncthreads();
    if (wA >= 0 && t < 64) {
      int w = wA; unsigned exw = kexA;
      unsigned v = (t < 16) ? hc[w * 16 + t] : 0u;
      unsigned sufv = v;
#pragma unroll
      for (int off = 1; off < 16; off <<= 1) {
        unsigned x = __shfl_down(sufv, off, 64);
        if (t + off < 16) sufv += x;
      }
      unsigned excl2 = exw + (sufv - v);
      if (t < 16 && excl2 < k && k <= excl2 + v) {
        prefS |= ((unsigned)(w * 16 + t)) << shift;
        kS = k - excl2;
      }
    }
    __syncthreads();
  }
  unsigned Tu = prefS;   // exact threshold key value
  unsigned tie = kS;     // tie-valued keys to take
  float acc = 0.f;
  if (k0 > 0) {
    for (int n = 0; n < iters; n++) {
      int i = n * 1024 + t;
      if (i < NPRI) {
        unsigned kk = key[(size_t)b * NPRI + i];
        if (kk > Tu) acc += __uint_as_float(kk);  // uint order == float order (keys >= 0)
      }
    }
  }
#pragma unroll
  for (int off = 32; off; off >>= 1) acc += __shfl_down(acc, off, 64);
  if ((t & 63) == 0) redf[t >> 6] = acc;
  __syncthreads();
  if (t == 0) {
    float tot = 0.f;
    for (int wv = 0; wv < 16; wv++) tot += redf[wv];
    if (k0 > 0) tot += (float)tie * __uint_as_float(Tu);
    negsum[b] = tot;
    __threadfence();
    unsigned r2 = atomicAdd(final_tk, 1u);
    if (r2 == BATCH - 1) {                 // globally-last block combines
      __threadfence();
      float lb = 0.f, ctot = 0.f; unsigned tp = 0;
      for (int bb = 0; bb < BATCH; bb++) {
        lb += aload_f32(&sl1sum[bb]) / fmaxf((float)npos[bb], 1.f);
        tp += npos[bb];
        ctot += aload_f32(&cepos[bb]) + aload_f32(&negsum[bb]);
      }
      out[0] = (1.5f * lb + ctot / fmaxf((float)tp, 1.f)) / (float)BATCH;
      *final_tk = 0;                       // self-clean for next replay
    }
  }
}

extern "C" void kernel_launch(void* const* d_in, const int* in_sizes, int n_in,
                              void* d_out, int out_size, void* d_ws, size_t ws_size,
                              hipStream_t stream) {
  const float* loc = (const float*)d_in[0];
  const float* conf = (const float*)d_in[1];
  const float* priors = (const float*)d_in[2];
  const float* gtb = (const float*)d_in[3];
  const int* gtl = (const int*)d_in[4];
  char* ws = (char*)d_ws;
  unsigned* key = (unsigned*)(ws + OFF_KEY);
  unsigned long long* gtc = (unsigned long long*)(ws + OFF_GTC);
  unsigned* histg = (unsigned*)(ws + OFF_HG);
  unsigned* npos = (unsigned*)(ws + OFF_NPOS);
  float* sl1sum = (float*)(ws + OFF_SL1);
  float* cepos = (float*)(ws + OFF_CEP);
  float* negsum = (float*)(ws + OFF_NEG);
  unsigned* final_tk = (unsigned*)(ws + OFF_FTK);
  float* out = (float*)d_out;

  k_init<<<1, 512, 0, stream>>>(histg, gtc);
  dim3 gridM(MCHUNK, BATCH * NGT);
  k_match<<<gridM, TPB, 0, stream>>>(priors, gtb, gtc);
  dim3 gridC(CBLK, BATCH);
  k_conf<<<gridC, 256, 0, stream>>>(loc, conf, priors, gtb, gtl, gtc,
                                    key, histg, npos, sl1sum, cepos);
  k_select<<<BATCH, 1024, 0, stream>>>(key, histg, npos, sl1sum, cepos,
                                       negsum, final_tk, out);
}